// Round 8
// baseline (43.873 us; speedup 1.0000x reference)
//
#include <hip/hip_runtime.h>
#include <math.h>

// Problem constants
#define NB 16
#define NC 64
#define NL 4096            // 64*64
#define NCOUT 64
#define EPSF 1e-5f
#define LOG_EPSF -11.512925464970229f   // log(1e-5)
#define CC 4               // channels per chunk (= waves per block)
#define NCHUNK 16

// ACC = float4[4] (4 o's), MV = data l-vector, W = 4 o-weights
#define FMA16(ACC, MV, W) \
  (ACC)[0].x = fmaf((MV).x,(W).x,(ACC)[0].x); (ACC)[0].y = fmaf((MV).y,(W).x,(ACC)[0].y); \
  (ACC)[0].z = fmaf((MV).z,(W).x,(ACC)[0].z); (ACC)[0].w = fmaf((MV).w,(W).x,(ACC)[0].w); \
  (ACC)[1].x = fmaf((MV).x,(W).y,(ACC)[1].x); (ACC)[1].y = fmaf((MV).y,(W).y,(ACC)[1].y); \
  (ACC)[1].z = fmaf((MV).z,(W).y,(ACC)[1].z); (ACC)[1].w = fmaf((MV).w,(W).y,(ACC)[1].w); \
  (ACC)[2].x = fmaf((MV).x,(W).z,(ACC)[2].x); (ACC)[2].y = fmaf((MV).y,(W).z,(ACC)[2].y); \
  (ACC)[2].z = fmaf((MV).z,(W).z,(ACC)[2].z); (ACC)[2].w = fmaf((MV).w,(W).z,(ACC)[2].w); \
  (ACC)[3].x = fmaf((MV).x,(W).w,(ACC)[3].x); (ACC)[3].y = fmaf((MV).y,(W).w,(ACC)[3].y); \
  (ACC)[3].z = fmaf((MV).z,(W).w,(ACC)[3].z); (ACC)[3].w = fmaf((MV).w,(W).w,(ACC)[3].w);

__global__ __launch_bounds__(256, 4) void fused_kernel(
    const float* __restrict__ x_mag, const float* __restrict__ x_ang,
    const float* __restrict__ wm, const float* __restrict__ wa,
    const float* __restrict__ w1, const float* __restrict__ w2,
    float* __restrict__ out)
{
    // LDS ~38 KB -> 4 blocks/CU = 16 waves/CU in 4 INDEPENDENT barrier domains
    __shared__ __align__(16) float lfm[CC][3][72];      // staged log(fm+eps): rows iy-1..iy+1
    __shared__ __align__(16) float fas[CC][3][72];      // staged fa
    __shared__ __align__(16) float m1r[2][CC][64];      // conv out (mag), parity dbuf
    __shared__ __align__(16) float a1r[2][CC][64];      // conv out (ang)
    __shared__ __align__(16) float w2m[64][68];         // [c][o] w2^2/rowsum(o)  (w2a = w2m*rho[o])
    __shared__ float wm1s[64][9], wa1s[64][9];
    __shared__ float smag_s[64][9], tang_s[64][9];
    __shared__ float red[4][4];
    __shared__ __align__(16) float rho[64];             // rowsum(o)/globalsum

    const int tid  = threadIdx.x;
    const int lane = tid & 63;
    const int wv   = tid >> 6;           // 0..3

    // XCD swizzle: 1024 % 8 == 0 -> bijective; 128 consecutive bids (2 images) per XCD
    const int bid = (blockIdx.x & 7) * 128 + (blockIdx.x >> 3);
    const int b  = bid >> 6;
    const int iy = bid & 63;             // block owns output row iy

    // ---- stage mapping: wave wv stages channel (ch*CC+wv); lane -> (sr, j4) ----
    const int sr = lane >> 4;            // staged row 0..2 -> image row iy-1+sr (sr==3 idle)
    const int j4 = lane & 15;
    const bool act = (sr < 3);
    const int ir = iy - 1 + sr;
    const bool ok = act && ((unsigned)ir < 64u);
    const int irc = ok ? ir : 0;
    const int ci = (ir == 0) ? 0 : ((ir == 63) ? 2 : 1);
    const int kL = ci * 3 + 0, kC = ci * 3 + 1, kR = ci * 3 + 2;
    const float ni = (ci == 1) ? 3.f : 2.f;
    const float nCt = 3.f * ni;
    const float n0 = (j4 == 0)  ? 2.f * ni : nCt;
    const float n3 = (j4 == 15) ? 2.f * ni : nCt;

    const float* spm = x_mag + ((size_t)(b * NC + wv) * NL + irc * 64 + j4 * 4);
    const float* spa = x_ang + ((size_t)(b * NC + wv) * NL + irc * 64 + j4 * 4);

    // chunk-0 prefetch in flight across the whole weight prep
    float4 pfm, pfa;
    if (act) { pfm = *(const float4*)spm; pfa = *(const float4*)spa; }

    // ---- matmul mapping: tid = o16(b7-4) | l16(b3-0) ----
    const int o0 = (tid >> 4) * 4;
    const int l0 = (tid & 15) * 4;

    // ---------- per-block weight prep ----------
    float p0 = 0.f, p1 = 0.f, p2 = 0.f;
    {
        float v;
        v = wm[tid];       p0 += v * v;  v = wm[tid + 256]; p0 += v * v;
        v = wa[tid];       p1 += v * v;  v = wa[tid + 256]; p1 += v * v;
        v = w1[tid];       p2 += v * v;  v = w1[tid + 256]; p2 += v * v;
        if (tid < 64) {
            v = wm[tid + 512]; p0 += v * v;
            v = wa[tid + 512]; p1 += v * v;
            v = w1[tid + 512]; p2 += v * v;
        }
    }
    #pragma unroll
    for (int s = 32; s; s >>= 1) {
        p0 += __shfl_down(p0, s); p1 += __shfl_down(p1, s); p2 += __shfl_down(p2, s);
    }
    if (lane == 0) { red[0][wv] = p0; red[1][wv] = p1; red[2][wv] = p2; }

    // w2: transposed column loads (lane = c), per-o rowsums via 64-lane butterfly
    float sqv[4][4], r2v[4][4];
    float s22p = 0.f;
    #pragma unroll
    for (int k = 0; k < 4; ++k) {
        const int oq = wv + 4 * k;       // o-quad 0..15
        #pragma unroll
        for (int n = 0; n < 4; ++n) {
            float v = w2[(oq * 4 + n) * 64 + lane];
            float s = v * v;
            sqv[k][n] = s;
            float rr_ = s;
            rr_ += __shfl_xor(rr_, 1);  rr_ += __shfl_xor(rr_, 2);
            rr_ += __shfl_xor(rr_, 4);  rr_ += __shfl_xor(rr_, 8);
            rr_ += __shfl_xor(rr_, 16); rr_ += __shfl_xor(rr_, 32);
            r2v[k][n] = rr_;             // rowsum r2[o], broadcast to all lanes
        }
        s22p += r2v[k][0] + r2v[k][1] + r2v[k][2] + r2v[k][3];
    }
    if (lane == 0) red[3][wv] = s22p;
    __syncthreads();
    const float s_wm2 = red[0][0] + red[0][1] + red[0][2] + red[0][3];
    const float s_wa2 = red[1][0] + red[1][1] + red[1][2] + red[1][3];
    const float s_w12 = red[2][0] + red[2][1] + red[2][2] + red[2][3];
    const float inv_s22 = 1.f / (red[3][0] + red[3][1] + red[3][2] + red[3][3]);

    // normalized transposed w2m table + rho
    #pragma unroll
    for (int k = 0; k < 4; ++k) {
        const int oq = wv + 4 * k;
        float4 wmv4;
        wmv4.x = sqv[k][0] / r2v[k][0];
        wmv4.y = sqv[k][1] / r2v[k][1];
        wmv4.z = sqv[k][2] / r2v[k][2];
        wmv4.w = sqv[k][3] / r2v[k][3];
        *(float4*)&w2m[lane][oq * 4] = wmv4;
        if (lane == 0) {
            rho[oq * 4 + 0] = r2v[k][0] * inv_s22;
            rho[oq * 4 + 1] = r2v[k][1] * inv_s22;
            rho[oq * 4 + 2] = r2v[k][2] * inv_s22;
            rho[oq * 4 + 3] = r2v[k][3] * inv_s22;
        }
    }

    // w1 tables (wave 0) and boundary-class tables (wave 1)
    if (tid < 64) {
        const int c = tid;
        float q[9]; float r1c = 0.f;
        #pragma unroll
        for (int k = 0; k < 9; ++k) { float v = w1[c * 9 + k]; q[k] = v * v; r1c += q[k]; }
        float inv_r = 1.f / r1c, inv_s = 1.f / s_w12;
        #pragma unroll
        for (int k = 0; k < 9; ++k) { wm1s[c][k] = q[k] * inv_r; wa1s[c][k] = q[k] * inv_s; }
    } else if (tid < 128) {
        const int c = tid - 64;
        float nm[9], na[9];
        const float inv_m = 1.f / s_wm2, inv_a = 1.f / s_wa2;
        #pragma unroll
        for (int k = 0; k < 9; ++k) {
            float v = wm[c * 9 + k];
            nm[k] = v * v * inv_m;
            na[k] = wa[c * 9 + k] * inv_a;
        }
        #pragma unroll
        for (int ci_ = 0; ci_ < 3; ++ci_) {
            #pragma unroll
            for (int cj = 0; cj < 3; ++cj) {
                float sm = 0.f, sa = 0.f;
                #pragma unroll
                for (int ki = 0; ki < 3; ++ki) {
                    bool vi = (ci_ == 0) ? (ki < 2) : ((ci_ == 2) ? (ki > 0) : true);
                    if (!vi) continue;
                    #pragma unroll
                    for (int kj = 0; kj < 3; ++kj) {
                        bool vj = (cj == 0) ? (kj < 2) : ((cj == 2) ? (kj > 0) : true);
                        if (!vj) continue;
                        sm += nm[ki * 3 + kj];
                        sa += na[ki * 3 + kj];
                    }
                }
                smag_s[c][ci_ * 3 + cj] = sm;
                tang_s[c][ci_ * 3 + cj] = sa;
            }
        }
    }
    __syncthreads();

    // ---------- main channel loop ----------
    float4 accm[4], acca[4];             // 4 o's x 4 l's, both sides
    #pragma unroll
    for (int oi = 0; oi < 4; ++oi) {
        accm[oi].x = accm[oi].y = accm[oi].z = accm[oi].w = 0.f;
        acca[oi].x = acca[oi].y = acca[oi].z = acca[oi].w = 0.f;
    }

    auto do_matmul = [&](int chm, int pp) {
        const int c0 = chm * CC;
        __builtin_amdgcn_s_setprio(1);
        #pragma unroll
        for (int cc = 0; cc < CC; ++cc) {
            float4 mv  = *(const float4*)&m1r[pp][cc][l0];
            float4 av  = *(const float4*)&a1r[pp][cc][l0];
            float4 wmv = *(const float4*)&w2m[c0 + cc][o0];
            FMA16(accm, mv, wmv);
            FMA16(acca, av, wmv);        // ang uses same weights; *rho[o] in epilogue
        }
        __builtin_amdgcn_s_setprio(0);
    };

    #pragma unroll 2
    for (int ch = 0; ch < NCHUNK; ++ch) {
        const int p = ch & 1;
        const int cg = ch * CC + wv;

        // ---- stage(ch): wave-local, sr<3 lanes ----
        if (act) {
            float4 dm, da;
            if (ok) {
                float sC = smag_s[cg][kC], tC = tang_s[cg][kC];
                float s0 = (j4 == 0)  ? smag_s[cg][kL] : sC;
                float s3 = (j4 == 15) ? smag_s[cg][kR] : sC;
                float t0 = (j4 == 0)  ? tang_s[cg][kL] : tC;
                float t3 = (j4 == 15) ? tang_s[cg][kR] : tC;
                dm.x = __logf(fmaf(n0,  pfm.x, s0) + EPSF);
                dm.y = __logf(fmaf(nCt, pfm.y, sC) + EPSF);
                dm.z = __logf(fmaf(nCt, pfm.z, sC) + EPSF);
                dm.w = __logf(fmaf(n3,  pfm.w, s3) + EPSF);
                da.x = pfa.x * t0; da.y = pfa.y * tC;
                da.z = pfa.z * tC; da.w = pfa.w * t3;
            } else {
                dm.x = dm.y = dm.z = dm.w = LOG_EPSF;
                da.x = da.y = da.z = da.w = 0.f;
            }
            *(float4*)&lfm[wv][sr][4 + j4 * 4] = dm;
            *(float4*)&fas[wv][sr][4 + j4 * 4] = da;
            if (j4 == 0)  { lfm[wv][sr][3]  = LOG_EPSF; fas[wv][sr][3]  = 0.f; }
            if (j4 == 15) { lfm[wv][sr][68] = LOG_EPSF; fas[wv][sr][68] = 0.f; }
        }

        // ---- prefetch next chunk (in flight across matmul + conv) ----
        if (act && (ch + 1 < NCHUNK)) {
            pfm = *(const float4*)(spm + (size_t)(ch + 1) * CC * NL);
            pfa = *(const float4*)(spa + (size_t)(ch + 1) * CC * NL);
        }

        // ---- matmul(ch-1): reads parity p^1 ----
        if (ch > 0) do_matmul(ch - 1, p ^ 1);

        // ---- conv(ch): wave-local scalar (proven conflict-free) ----
        {
            float mres = 0.f, ares = 0.f;
            #pragma unroll
            for (int r_ = 0; r_ < 3; ++r_) {
                mres = fmaf(wm1s[cg][r_ * 3 + 0], lfm[wv][r_][lane + 3], mres);
                mres = fmaf(wm1s[cg][r_ * 3 + 1], lfm[wv][r_][lane + 4], mres);
                mres = fmaf(wm1s[cg][r_ * 3 + 2], lfm[wv][r_][lane + 5], mres);
                ares = fmaf(wa1s[cg][r_ * 3 + 0], fas[wv][r_][lane + 3], ares);
                ares = fmaf(wa1s[cg][r_ * 3 + 1], fas[wv][r_][lane + 4], ares);
                ares = fmaf(wa1s[cg][r_ * 3 + 2], fas[wv][r_][lane + 5], ares);
            }
            m1r[p][wv][lane] = mres;
            a1r[p][wv][lane] = ares;
        }
        __syncthreads();   // ONE barrier per chunk: fences m1r/a1r[p]
    }
    do_matmul(NCHUNK - 1, 1);

    // ---------- epilogue ----------
    const float4 rh4 = *(const float4*)&rho[o0];
    acca[0].x *= rh4.x; acca[0].y *= rh4.x; acca[0].z *= rh4.x; acca[0].w *= rh4.x;
    acca[1].x *= rh4.y; acca[1].y *= rh4.y; acca[1].z *= rh4.y; acca[1].w *= rh4.y;
    acca[2].x *= rh4.z; acca[2].y *= rh4.z; acca[2].z *= rh4.z; acca[2].w *= rh4.z;
    acca[3].x *= rh4.w; acca[3].y *= rh4.w; acca[3].z *= rh4.w; acca[3].w *= rh4.w;

    #pragma unroll
    for (int oi = 0; oi < 4; ++oi) {
        float4 am = accm[oi], aa = acca[oi];
        float4 oc, os;
        float ex;
        ex = __expf(am.x); oc.x = ex * __cosf(aa.x); os.x = ex * __sinf(aa.x);
        ex = __expf(am.y); oc.y = ex * __cosf(aa.y); os.y = ex * __sinf(aa.y);
        ex = __expf(am.z); oc.z = ex * __cosf(aa.z); os.z = ex * __sinf(aa.z);
        ex = __expf(am.w); oc.w = ex * __cosf(aa.w); os.w = ex * __sinf(aa.w);
        size_t gi = ((size_t)(b * 2) * NCOUT + o0 + oi) * NL + (size_t)iy * 64 + l0;
        *(float4*)&out[gi] = oc;
        *(float4*)&out[gi + (size_t)NCOUT * NL] = os;
    }
}

extern "C" void kernel_launch(void* const* d_in, const int* in_sizes, int n_in,
                              void* d_out, int out_size, void* d_ws, size_t ws_size,
                              hipStream_t stream) {
    const float* x_mag = (const float*)d_in[0];
    const float* x_ang = (const float*)d_in[1];
    const float* w_mag = (const float*)d_in[2];
    const float* w_ang = (const float*)d_in[3];
    const float* w1    = (const float*)d_in[4];
    const float* w2    = (const float*)d_in[5];
    float* out = (float*)d_out;

    fused_kernel<<<NB * 64, 256, 0, stream>>>(x_mag, x_ang, w_mag, w_ang, w1, w2, out);
}

// Round 9
// 39.971 us; speedup vs baseline: 1.0976x; 1.0976x over previous
//
#include <hip/hip_runtime.h>
#include <math.h>

// Problem constants
#define NB 16
#define NC 64
#define NL 4096            // 64*64
#define NCOUT 64
#define EPSF 1e-5f
#define LOG_EPSF -11.512925464970229f   // log(1e-5)
#define CC 4               // channels per chunk (= waves per block)
#define NCHUNK 16

// ACC = float4[4] (4 o's), MV = data l-vector, W = 4 o-weights
#define FMA16(ACC, MV, W) \
  (ACC)[0].x = fmaf((MV).x,(W).x,(ACC)[0].x); (ACC)[0].y = fmaf((MV).y,(W).x,(ACC)[0].y); \
  (ACC)[0].z = fmaf((MV).z,(W).x,(ACC)[0].z); (ACC)[0].w = fmaf((MV).w,(W).x,(ACC)[0].w); \
  (ACC)[1].x = fmaf((MV).x,(W).y,(ACC)[1].x); (ACC)[1].y = fmaf((MV).y,(W).y,(ACC)[1].y); \
  (ACC)[1].z = fmaf((MV).z,(W).y,(ACC)[1].z); (ACC)[1].w = fmaf((MV).w,(W).y,(ACC)[1].w); \
  (ACC)[2].x = fmaf((MV).x,(W).z,(ACC)[2].x); (ACC)[2].y = fmaf((MV).y,(W).z,(ACC)[2].y); \
  (ACC)[2].z = fmaf((MV).z,(W).z,(ACC)[2].z); (ACC)[2].w = fmaf((MV).w,(W).z,(ACC)[2].w); \
  (ACC)[3].x = fmaf((MV).x,(W).w,(ACC)[3].x); (ACC)[3].y = fmaf((MV).y,(W).w,(ACC)[3].y); \
  (ACC)[3].z = fmaf((MV).z,(W).w,(ACC)[3].z); (ACC)[3].w = fmaf((MV).w,(W).w,(ACC)[3].w);

__global__ __launch_bounds__(256, 2) void fused_kernel(
    const float* __restrict__ x_mag, const float* __restrict__ x_ang,
    const float* __restrict__ wm, const float* __restrict__ wa,
    const float* __restrict__ w1, const float* __restrict__ w2,
    float* __restrict__ out)
{
    // LDS ~39.7 KB; grid 512 -> 2 blocks/CU, 8 waves/CU
    __shared__ __align__(16) float lfm[CC][4][72];      // staged log(fm+eps): rows i0-1..i0+2
    __shared__ __align__(16) float fas[CC][4][72];      // staged fa
    __shared__ __align__(16) float m1r[2][CC][2][64];   // conv out (mag), parity dbuf
    __shared__ __align__(16) float a1r[2][CC][2][64];   // conv out (ang)
    __shared__ __align__(16) float w2m[64][68];         // [c][o] w2^2/rowsum(o)  (w2a = w2m*rho[o])
    __shared__ float smag_s[64][9], tang_s[64][9];      // boundary-class sums
    __shared__ float red[4][4];
    __shared__ __align__(16) float rho[64];             // rowsum(o)/globalsum

    const int tid  = threadIdx.x;
    const int lane = tid & 63;
    const int wv   = tid >> 6;           // 0..3

    // XCD swizzle: 512 % 8 == 0 -> bijective; 64 consecutive bids (2 images) per XCD
    const int bid = (blockIdx.x & 7) * 64 + (blockIdx.x >> 3);
    const int b  = bid >> 5;
    const int i0 = (bid & 31) * 2;       // block owns output rows i0, i0+1

    // ---- stage mapping: wave wv stages channel (ch*CC+wv); lane -> (sr, j4) ----
    const int sr = lane >> 4;            // staged row 0..3 -> image row i0-1+sr
    const int j4 = lane & 15;
    const int ir = i0 - 1 + sr;
    const bool ok = ((unsigned)ir < 64u);
    const int irc = ok ? ir : 0;
    const int ci = (ir == 0) ? 0 : ((ir == 63) ? 2 : 1);
    const int kL = ci * 3 + 0, kC = ci * 3 + 1, kR = ci * 3 + 2;
    const float ni = (ci == 1) ? 3.f : 2.f;
    const float nCt = 3.f * ni;
    const float n0 = (j4 == 0)  ? 2.f * ni : nCt;
    const float n3 = (j4 == 15) ? 2.f * ni : nCt;

    const float* spm = x_mag + ((size_t)(b * NC + wv) * NL + irc * 64 + j4 * 4);
    const float* spa = x_ang + ((size_t)(b * NC + wv) * NL + irc * 64 + j4 * 4);

    // chunk-0 prefetch in flight across the whole weight prep
    float4 pfm = *(const float4*)spm;
    float4 pfa = *(const float4*)spa;

    // ---- matmul mapping: tid = rr(b7) | o8(b6-4) | l16(b3-0); 8o x 4l tile ----
    const int mrr = tid >> 7;
    const int o0  = ((tid >> 4) & 7) * 8;
    const int l0  = (tid & 15) * 4;

    // ---------- per-block weight prep ----------
    float p0 = 0.f, p1 = 0.f, p2 = 0.f;
    {
        float v;
        v = wm[tid];       p0 += v * v;  v = wm[tid + 256]; p0 += v * v;
        v = wa[tid];       p1 += v * v;  v = wa[tid + 256]; p1 += v * v;
        v = w1[tid];       p2 += v * v;  v = w1[tid + 256]; p2 += v * v;
        if (tid < 64) {
            v = wm[tid + 512]; p0 += v * v;
            v = wa[tid + 512]; p1 += v * v;
            v = w1[tid + 512]; p2 += v * v;
        }
    }
    #pragma unroll
    for (int s = 32; s; s >>= 1) {
        p0 += __shfl_down(p0, s); p1 += __shfl_down(p1, s); p2 += __shfl_down(p2, s);
    }
    if (lane == 0) { red[0][wv] = p0; red[1][wv] = p1; red[2][wv] = p2; }

    // w2: transposed column loads (lane = c), per-o rowsums via 64-lane butterfly
    float sqv[4][4], r2v[4][4];
    float s22p = 0.f;
    #pragma unroll
    for (int k = 0; k < 4; ++k) {
        const int oq = wv + 4 * k;       // o-quad 0..15
        #pragma unroll
        for (int n = 0; n < 4; ++n) {
            float v = w2[(oq * 4 + n) * 64 + lane];
            float s = v * v;
            sqv[k][n] = s;
            float rr_ = s;
            rr_ += __shfl_xor(rr_, 1);  rr_ += __shfl_xor(rr_, 2);
            rr_ += __shfl_xor(rr_, 4);  rr_ += __shfl_xor(rr_, 8);
            rr_ += __shfl_xor(rr_, 16); rr_ += __shfl_xor(rr_, 32);
            r2v[k][n] = rr_;             // rowsum r2[o], broadcast to all lanes
        }
        s22p += r2v[k][0] + r2v[k][1] + r2v[k][2] + r2v[k][3];
    }
    if (lane == 0) red[3][wv] = s22p;
    __syncthreads();
    const float s_wm2 = red[0][0] + red[0][1] + red[0][2] + red[0][3];
    const float s_wa2 = red[1][0] + red[1][1] + red[1][2] + red[1][3];
    const float s_w12 = red[2][0] + red[2][1] + red[2][2] + red[2][3];
    const float inv_s22 = 1.f / (red[3][0] + red[3][1] + red[3][2] + red[3][3]);
    const float inv_s12 = 1.f / s_w12;

    // normalized transposed w2m table + rho
    #pragma unroll
    for (int k = 0; k < 4; ++k) {
        const int oq = wv + 4 * k;
        float4 wmv4;
        wmv4.x = sqv[k][0] / r2v[k][0];
        wmv4.y = sqv[k][1] / r2v[k][1];
        wmv4.z = sqv[k][2] / r2v[k][2];
        wmv4.w = sqv[k][3] / r2v[k][3];
        *(float4*)&w2m[lane][oq * 4] = wmv4;
        if (lane == 0) {
            rho[oq * 4 + 0] = r2v[k][0] * inv_s22;
            rho[oq * 4 + 1] = r2v[k][1] * inv_s22;
            rho[oq * 4 + 2] = r2v[k][2] * inv_s22;
            rho[oq * 4 + 3] = r2v[k][3] * inv_s22;
        }
    }

    // boundary-class tables (wave 1)
    if (tid >= 64 && tid < 128) {
        const int c = tid - 64;
        float nm[9], na[9];
        const float inv_m = 1.f / s_wm2, inv_a = 1.f / s_wa2;
        #pragma unroll
        for (int k = 0; k < 9; ++k) {
            float v = wm[c * 9 + k];
            nm[k] = v * v * inv_m;
            na[k] = wa[c * 9 + k] * inv_a;
        }
        #pragma unroll
        for (int ci_ = 0; ci_ < 3; ++ci_) {
            #pragma unroll
            for (int cj = 0; cj < 3; ++cj) {
                float sm = 0.f, sa = 0.f;
                #pragma unroll
                for (int ki = 0; ki < 3; ++ki) {
                    bool vi = (ci_ == 0) ? (ki < 2) : ((ci_ == 2) ? (ki > 0) : true);
                    if (!vi) continue;
                    #pragma unroll
                    for (int kj = 0; kj < 3; ++kj) {
                        bool vj = (cj == 0) ? (kj < 2) : ((cj == 2) ? (kj > 0) : true);
                        if (!vj) continue;
                        sm += nm[ki * 3 + kj];
                        sa += na[ki * 3 + kj];
                    }
                }
                smag_s[c][ci_ * 3 + cj] = sm;
                tang_s[c][ci_ * 3 + cj] = sa;
            }
        }
    }

    // chunk-invariant sentinel/pad writes (wave-local; hoisted out of the loop)
    if (j4 == 0)  { lfm[wv][sr][3]  = LOG_EPSF; fas[wv][sr][3]  = 0.f; }
    if (j4 == 15) { lfm[wv][sr][68] = LOG_EPSF; fas[wv][sr][68] = 0.f; }
    if (!ok) {
        float4 sm4; sm4.x = sm4.y = sm4.z = sm4.w = LOG_EPSF;
        float4 z4;  z4.x = z4.y = z4.z = z4.w = 0.f;
        *(float4*)&lfm[wv][sr][4 + j4 * 4] = sm4;
        *(float4*)&fas[wv][sr][4 + j4 * 4] = z4;
    }
    __syncthreads();

    // ---------- main channel loop ----------
    float4 accm[8], acca[8];             // 8 o's x 4 l's, one row, both sides
    #pragma unroll
    for (int oi = 0; oi < 8; ++oi) {
        accm[oi].x = accm[oi].y = accm[oi].z = accm[oi].w = 0.f;
        acca[oi].x = acca[oi].y = acca[oi].z = acca[oi].w = 0.f;
    }

    auto do_matmul = [&](int chm, int pp) {
        const int c0 = chm * CC;
        #pragma unroll
        for (int cc = 0; cc < CC; ++cc) {
            float4 mv  = *(const float4*)&m1r[pp][cc][mrr][l0];
            float4 av  = *(const float4*)&a1r[pp][cc][mrr][l0];
            float4 w0_ = *(const float4*)&w2m[c0 + cc][o0];
            float4 w1_ = *(const float4*)&w2m[c0 + cc][o0 + 4];
            FMA16((&accm[0]), mv, w0_);
            FMA16((&accm[4]), mv, w1_);
            FMA16((&acca[0]), av, w0_);
            FMA16((&acca[4]), av, w1_);  // ang uses same weights; *rho[o] in epilogue
        }
    };

    #pragma unroll 2
    for (int ch = 0; ch < NCHUNK; ++ch) {
        const int p = ch & 1;
        const int cg = ch * CC + wv;

        // ---- conv weights: wave-uniform scalar loads from global (no LDS) ----
        const int cgu = __builtin_amdgcn_readfirstlane(cg);
        const float* w1row = w1 + cgu * 9;
        float q[9];
        #pragma unroll
        for (int k = 0; k < 9; ++k) q[k] = w1row[k];

        // ---- stage(ch): wave-local ----
        if (ok) {
            float sC = smag_s[cg][kC], tC = tang_s[cg][kC];
            float s0 = (j4 == 0)  ? smag_s[cg][kL] : sC;
            float s3 = (j4 == 15) ? smag_s[cg][kR] : sC;
            float t0 = (j4 == 0)  ? tang_s[cg][kL] : tC;
            float t3 = (j4 == 15) ? tang_s[cg][kR] : tC;
            float4 dm, da;
            dm.x = __logf(fmaf(n0,  pfm.x, s0) + EPSF);
            dm.y = __logf(fmaf(nCt, pfm.y, sC) + EPSF);
            dm.z = __logf(fmaf(nCt, pfm.z, sC) + EPSF);
            dm.w = __logf(fmaf(n3,  pfm.w, s3) + EPSF);
            da.x = pfa.x * t0; da.y = pfa.y * tC;
            da.z = pfa.z * tC; da.w = pfa.w * t3;
            *(float4*)&lfm[wv][sr][4 + j4 * 4] = dm;
            *(float4*)&fas[wv][sr][4 + j4 * 4] = da;
        }

        // ---- prefetch next chunk (in flight across matmul + conv) ----
        if (ch + 1 < NCHUNK) {
            pfm = *(const float4*)(spm + (size_t)(ch + 1) * CC * NL);
            pfa = *(const float4*)(spa + (size_t)(ch + 1) * CC * NL);
        }

        // ---- matmul(ch-1): reads parity p^1 ----
        if (ch > 0) do_matmul(ch - 1, p ^ 1);

        // ---- finish conv weights (VALU; s_loads have landed by now) ----
        #pragma unroll
        for (int k = 0; k < 9; ++k) q[k] = q[k] * q[k];
        const float r1c = ((q[0] + q[1]) + (q[2] + q[3])) + ((q[4] + q[5]) + (q[6] + q[7])) + q[8];
        const float inv_r1 = 1.f / r1c;

        // ---- conv(ch): wave-local scalar reads (proven conflict-free),
        //      unnormalized accumulate, scale at write ----
        {
            float mres0 = 0.f, mres1 = 0.f, ares0 = 0.f, ares1 = 0.f;
            #pragma unroll
            for (int r_ = 0; r_ < 4; ++r_) {
                float l0v = lfm[wv][r_][lane + 3];
                float l1v = lfm[wv][r_][lane + 4];
                float l2v = lfm[wv][r_][lane + 5];
                float a0v = fas[wv][r_][lane + 3];
                float a1v = fas[wv][r_][lane + 4];
                float a2v = fas[wv][r_][lane + 5];
                if (r_ < 3) {   // output row i0, ki = r_
                    mres0 = fmaf(q[r_ * 3 + 0], l0v, mres0);
                    mres0 = fmaf(q[r_ * 3 + 1], l1v, mres0);
                    mres0 = fmaf(q[r_ * 3 + 2], l2v, mres0);
                    ares0 = fmaf(q[r_ * 3 + 0], a0v, ares0);
                    ares0 = fmaf(q[r_ * 3 + 1], a1v, ares0);
                    ares0 = fmaf(q[r_ * 3 + 2], a2v, ares0);
                }
                if (r_ > 0) {   // output row i0+1, ki = r_-1
                    const int ki = r_ - 1;
                    mres1 = fmaf(q[ki * 3 + 0], l0v, mres1);
                    mres1 = fmaf(q[ki * 3 + 1], l1v, mres1);
                    mres1 = fmaf(q[ki * 3 + 2], l2v, mres1);
                    ares1 = fmaf(q[ki * 3 + 0], a0v, ares1);
                    ares1 = fmaf(q[ki * 3 + 1], a1v, ares1);
                    ares1 = fmaf(q[ki * 3 + 2], a2v, ares1);
                }
            }
            m1r[p][wv][0][lane] = mres0 * inv_r1;
            m1r[p][wv][1][lane] = mres1 * inv_r1;
            a1r[p][wv][0][lane] = ares0 * inv_s12;
            a1r[p][wv][1][lane] = ares1 * inv_s12;
        }
        __syncthreads();   // ONE barrier per chunk: fences m1r/a1r[p]
    }
    do_matmul(NCHUNK - 1, 1);

    // ---------- epilogue ----------
    {
        const float4 rh0 = *(const float4*)&rho[o0];
        const float4 rh1 = *(const float4*)&rho[o0 + 4];
        acca[0].x *= rh0.x; acca[0].y *= rh0.x; acca[0].z *= rh0.x; acca[0].w *= rh0.x;
        acca[1].x *= rh0.y; acca[1].y *= rh0.y; acca[1].z *= rh0.y; acca[1].w *= rh0.y;
        acca[2].x *= rh0.z; acca[2].y *= rh0.z; acca[2].z *= rh0.z; acca[2].w *= rh0.z;
        acca[3].x *= rh0.w; acca[3].y *= rh0.w; acca[3].z *= rh0.w; acca[3].w *= rh0.w;
        acca[4].x *= rh1.x; acca[4].y *= rh1.x; acca[4].z *= rh1.x; acca[4].w *= rh1.x;
        acca[5].x *= rh1.y; acca[5].y *= rh1.y; acca[5].z *= rh1.y; acca[5].w *= rh1.y;
        acca[6].x *= rh1.z; acca[6].y *= rh1.z; acca[6].z *= rh1.z; acca[6].w *= rh1.z;
        acca[7].x *= rh1.w; acca[7].y *= rh1.w; acca[7].z *= rh1.w; acca[7].w *= rh1.w;
    }

    #pragma unroll
    for (int oi = 0; oi < 8; ++oi) {
        float4 am = accm[oi], aa = acca[oi];
        float4 oc, os;
        float ex;
        ex = __expf(am.x); oc.x = ex * __cosf(aa.x); os.x = ex * __sinf(aa.x);
        ex = __expf(am.y); oc.y = ex * __cosf(aa.y); os.y = ex * __sinf(aa.y);
        ex = __expf(am.z); oc.z = ex * __cosf(aa.z); os.z = ex * __sinf(aa.z);
        ex = __expf(am.w); oc.w = ex * __cosf(aa.w); os.w = ex * __sinf(aa.w);
        size_t gi = ((size_t)(b * 2) * NCOUT + o0 + oi) * NL + (size_t)(i0 + mrr) * 64 + l0;
        *(float4*)&out[gi] = oc;
        *(float4*)&out[gi + (size_t)NCOUT * NL] = os;
    }
}

extern "C" void kernel_launch(void* const* d_in, const int* in_sizes, int n_in,
                              void* d_out, int out_size, void* d_ws, size_t ws_size,
                              hipStream_t stream) {
    const float* x_mag = (const float*)d_in[0];
    const float* x_ang = (const float*)d_in[1];
    const float* w_mag = (const float*)d_in[2];
    const float* w_ang = (const float*)d_in[3];
    const float* w1    = (const float*)d_in[4];
    const float* w2    = (const float*)d_in[5];
    float* out = (float*)d_out;

    fused_kernel<<<NB * 32, 256, 0, stream>>>(x_mag, x_ang, w_mag, w_ang, w1, w2, out);
}